// Round 1
// baseline (3223.737 us; speedup 1.0000x reference)
//
#include <hip/hip_runtime.h>

// Problem constants (from the reference)
#define NNZ_TOT   1048576
#define N_IN_SZ   (721 * 1440)   // 1,038,240
#define N_OUT_SZ  (361 * 720)    //   259,920
#define BC        64             // B*C = 4*16

// One (b,c) plane per blockIdx.y; grid-stride over nonzeros in x.
// Reads of S/rows/cols are coalesced; x gather is random 4B within a
// 4.15 MB plane (L2/L3 resident); atomicAdd lands in a 1 MB y plane.
__global__ void regrid_coo_kernel(const float* __restrict__ x,
                                  const float* __restrict__ S,
                                  const int*   __restrict__ rows,
                                  const int*   __restrict__ cols,
                                  float*       __restrict__ y,
                                  int nnz) {
    const int bc = blockIdx.y;
    const float* __restrict__ xp = x + (size_t)bc * N_IN_SZ;
    float*       __restrict__ yp = y + (size_t)bc * N_OUT_SZ;

    int k = blockIdx.x * blockDim.x + threadIdx.x;
    const int stride = gridDim.x * blockDim.x;
    for (; k < nnz; k += stride) {
        const int r = rows[k];
        const int c = cols[k];
        const float v = S[k] * xp[c];
        atomicAdd(&yp[r], v);
    }
}

extern "C" void kernel_launch(void* const* d_in, const int* in_sizes, int n_in,
                              void* d_out, int out_size, void* d_ws, size_t ws_size,
                              hipStream_t stream) {
    const float* x    = (const float*)d_in[0];   // [B, C, N_IN] f32
    const float* S    = (const float*)d_in[1];   // [NNZ] f32
    const int*   rows = (const int*)d_in[2];     // [NNZ] i32
    const int*   cols = (const int*)d_in[3];     // [NNZ] i32
    float*       y    = (float*)d_out;           // [B, C, N_OUT] f32

    const int nnz = in_sizes[1];

    // Zero the output (harness poisons it; we accumulate with atomics).
    hipMemsetAsync(d_out, 0, (size_t)out_size * sizeof(float), stream);

    const int block = 256;
    const int kblocks = 1024;                    // 1024*256 threads -> 4 k's/thread
    dim3 grid(kblocks, BC, 1);
    regrid_coo_kernel<<<grid, block, 0, stream>>>(x, S, rows, cols, y, nnz);
}

// Round 2
// 1233.893 us; speedup vs baseline: 2.6127x; 2.6127x over previous
//
#include <hip/hip_runtime.h>

// Problem constants (from the reference)
#define NNZ_TOT   1048576
#define N_IN_SZ   (721 * 1440)   // 1,038,240
#define N_ROWS    (361 * 720)    //   259,920 output cells
#define BC        64             // B*C = 4*16
#define ILP       4              // bc planes per gather thread

// ---------------- CSR build ----------------

__global__ void hist_kernel(const int* __restrict__ rows, int* __restrict__ counts, int nnz) {
    int k = blockIdx.x * blockDim.x + threadIdx.x;
    if (k < nnz) atomicAdd(&counts[rows[k]], 1);
}

// scan1: per-block exclusive scan of counts (chunk = 1024 elems / block), block totals -> aux
__global__ void scan1_kernel(const int* __restrict__ counts, int* __restrict__ excl,
                             int* __restrict__ aux, int n) {
    __shared__ int sdata[256];
    const int t = threadIdx.x;
    const int base = blockIdx.x * 1024 + t * 4;
    int v[4];
    #pragma unroll
    for (int j = 0; j < 4; ++j) {
        int idx = base + j;
        v[j] = (idx < n) ? counts[idx] : 0;
    }
    int tsum = v[0] + v[1] + v[2] + v[3];
    sdata[t] = tsum;
    __syncthreads();
    // Hillis-Steele inclusive scan over 256 thread sums
    for (int off = 1; off < 256; off <<= 1) {
        int xv = (t >= off) ? sdata[t - off] : 0;
        __syncthreads();
        sdata[t] += xv;
        __syncthreads();
    }
    int run = sdata[t] - tsum;   // exclusive prefix for this thread's chunk
    if (t == 255) aux[blockIdx.x] = sdata[255];
    #pragma unroll
    for (int j = 0; j < 4; ++j) {
        int idx = base + j;
        if (idx < n) excl[idx] = run;
        run += v[j];
    }
}

// scan2: single-block exclusive scan of aux (numBlocks <= 256)
__global__ void scan2_kernel(int* __restrict__ aux, int n2) {
    __shared__ int sdata[256];
    const int t = threadIdx.x;
    int a = (t < n2) ? aux[t] : 0;
    sdata[t] = a;
    __syncthreads();
    for (int off = 1; off < 256; off <<= 1) {
        int xv = (t >= off) ? sdata[t - off] : 0;
        __syncthreads();
        sdata[t] += xv;
        __syncthreads();
    }
    if (t < n2) aux[t] = sdata[t] - a;  // exclusive
}

// scan3: add block offsets; finalize row_ptr[n] = nnz
__global__ void scan3_kernel(int* __restrict__ row_ptr, const int* __restrict__ aux,
                             int n, int nnz) {
    const int add = aux[blockIdx.x];
    const int base = blockIdx.x * 1024 + threadIdx.x * 4;
    #pragma unroll
    for (int j = 0; j < 4; ++j) {
        int idx = base + j;
        if (idx < n) row_ptr[idx] += add;
    }
    if (blockIdx.x == 0 && threadIdx.x == 0) row_ptr[n] = nnz;
}

__global__ void scatter_kernel(const int* __restrict__ rows, const int* __restrict__ cols,
                               const float* __restrict__ S, const int* __restrict__ row_ptr,
                               int* __restrict__ cursor, int* __restrict__ ecol,
                               float* __restrict__ eval, int nnz) {
    int k = blockIdx.x * blockDim.x + threadIdx.x;
    if (k < nnz) {
        int r = rows[k];
        int p = row_ptr[r] + atomicAdd(&cursor[r], 1);
        ecol[p] = cols[k];
        eval[p] = S[k];
    }
}

// ---------------- gather: one thread = one output row x ILP bc planes ----------------

__global__ void gather_kernel(const float* __restrict__ x, const int* __restrict__ row_ptr,
                              const int* __restrict__ ecol, const float* __restrict__ eval,
                              float* __restrict__ y) {
    const int i = blockIdx.x * blockDim.x + threadIdx.x;
    if (i >= N_ROWS) return;
    const int bc0 = blockIdx.y * ILP;
    const float* __restrict__ xp0 = x + (size_t)bc0 * N_IN_SZ;

    const int s = row_ptr[i];
    const int e = row_ptr[i + 1];
    float acc[ILP] = {0.f, 0.f, 0.f, 0.f};
    for (int t = s; t < e; ++t) {
        const int c = ecol[t];
        const float w = eval[t];
        #pragma unroll
        for (int j = 0; j < ILP; ++j)
            acc[j] += w * xp0[(size_t)j * N_IN_SZ + c];
    }
    #pragma unroll
    for (int j = 0; j < ILP; ++j)
        y[(size_t)(bc0 + j) * N_ROWS + i] = acc[j];
}

// ---------------- fallback (round-1 atomic COO) if ws too small ----------------

__global__ void regrid_coo_kernel(const float* __restrict__ x, const float* __restrict__ S,
                                  const int* __restrict__ rows, const int* __restrict__ cols,
                                  float* __restrict__ y, int nnz) {
    const int bc = blockIdx.y;
    const float* __restrict__ xp = x + (size_t)bc * N_IN_SZ;
    float* __restrict__ yp = y + (size_t)bc * N_ROWS;
    int k = blockIdx.x * blockDim.x + threadIdx.x;
    const int stride = gridDim.x * blockDim.x;
    for (; k < nnz; k += stride) {
        atomicAdd(&yp[rows[k]], S[k] * xp[cols[k]]);
    }
}

extern "C" void kernel_launch(void* const* d_in, const int* in_sizes, int n_in,
                              void* d_out, int out_size, void* d_ws, size_t ws_size,
                              hipStream_t stream) {
    const float* x    = (const float*)d_in[0];
    const float* S    = (const float*)d_in[1];
    const int*   rows = (const int*)d_in[2];
    const int*   cols = (const int*)d_in[3];
    float*       y    = (float*)d_out;
    const int nnz = in_sizes[1];

    // Workspace layout (256B-aligned chunks)
    const size_t SZ_COUNTS = ((size_t)N_ROWS * 4 + 255) & ~255ULL;
    const size_t SZ_RPTR   = ((size_t)(N_ROWS + 1) * 4 + 255) & ~255ULL;
    const size_t SZ_CURSOR = SZ_COUNTS;
    const size_t SZ_AUX    = 1024;
    const size_t SZ_ECOL   = ((size_t)nnz * 4 + 255) & ~255ULL;
    const size_t SZ_EVAL   = SZ_ECOL;
    const size_t NEED = SZ_COUNTS + SZ_RPTR + SZ_CURSOR + SZ_AUX + SZ_ECOL + SZ_EVAL;

    if (ws_size < NEED) {
        // fallback: atomic COO (slow but correct)
        hipMemsetAsync(d_out, 0, (size_t)out_size * sizeof(float), stream);
        dim3 grid(1024, BC, 1);
        regrid_coo_kernel<<<grid, 256, 0, stream>>>(x, S, rows, cols, y, nnz);
        return;
    }

    char* w = (char*)d_ws;
    int*   counts  = (int*)(w);
    int*   row_ptr = (int*)(w + SZ_COUNTS);
    int*   cursor  = (int*)(w + SZ_COUNTS + SZ_RPTR);
    int*   aux     = (int*)(w + SZ_COUNTS + SZ_RPTR + SZ_CURSOR);
    int*   ecol    = (int*)(w + SZ_COUNTS + SZ_RPTR + SZ_CURSOR + SZ_AUX);
    float* eval    = (float*)(w + SZ_COUNTS + SZ_RPTR + SZ_CURSOR + SZ_AUX + SZ_ECOL);

    hipMemsetAsync(counts, 0, SZ_COUNTS, stream);
    hipMemsetAsync(cursor, 0, SZ_CURSOR, stream);

    const int nnzBlocks = (nnz + 255) / 256;
    const int scanBlocks = (N_ROWS + 1023) / 1024;  // 254

    hist_kernel<<<nnzBlocks, 256, 0, stream>>>(rows, counts, nnz);
    scan1_kernel<<<scanBlocks, 256, 0, stream>>>(counts, row_ptr, aux, N_ROWS);
    scan2_kernel<<<1, 256, 0, stream>>>(aux, scanBlocks);
    scan3_kernel<<<scanBlocks, 256, 0, stream>>>(row_ptr, aux, N_ROWS, nnz);
    scatter_kernel<<<nnzBlocks, 256, 0, stream>>>(rows, cols, S, row_ptr, cursor, ecol, eval, nnz);

    dim3 ggrid((N_ROWS + 255) / 256, BC / ILP, 1);
    gather_kernel<<<ggrid, 256, 0, stream>>>(x, row_ptr, ecol, eval, y);
}

// Round 3
// 590.056 us; speedup vs baseline: 5.4634x; 2.0911x over previous
//
#include <hip/hip_runtime.h>

// Problem constants (from the reference)
#define NNZ_TOT   1048576
#define N_IN_SZ   (721 * 1440)   // 1,038,240
#define N_ROWS    (361 * 720)    //   259,920 output cells
#define BC        64             // B*C = 4*16
#define ILP       4              // bc planes per thread (fallback gather)

// ---------------- CSR build ----------------

__global__ void hist_kernel(const int* __restrict__ rows, int* __restrict__ counts, int nnz) {
    int k = blockIdx.x * blockDim.x + threadIdx.x;
    if (k < nnz) atomicAdd(&counts[rows[k]], 1);
}

__global__ void scan1_kernel(const int* __restrict__ counts, int* __restrict__ excl,
                             int* __restrict__ aux, int n) {
    __shared__ int sdata[256];
    const int t = threadIdx.x;
    const int base = blockIdx.x * 1024 + t * 4;
    int v[4];
    #pragma unroll
    for (int j = 0; j < 4; ++j) {
        int idx = base + j;
        v[j] = (idx < n) ? counts[idx] : 0;
    }
    int tsum = v[0] + v[1] + v[2] + v[3];
    sdata[t] = tsum;
    __syncthreads();
    for (int off = 1; off < 256; off <<= 1) {
        int xv = (t >= off) ? sdata[t - off] : 0;
        __syncthreads();
        sdata[t] += xv;
        __syncthreads();
    }
    int run = sdata[t] - tsum;
    if (t == 255) aux[blockIdx.x] = sdata[255];
    #pragma unroll
    for (int j = 0; j < 4; ++j) {
        int idx = base + j;
        if (idx < n) excl[idx] = run;
        run += v[j];
    }
}

__global__ void scan2_kernel(int* __restrict__ aux, int n2) {
    __shared__ int sdata[256];
    const int t = threadIdx.x;
    int a = (t < n2) ? aux[t] : 0;
    sdata[t] = a;
    __syncthreads();
    for (int off = 1; off < 256; off <<= 1) {
        int xv = (t >= off) ? sdata[t - off] : 0;
        __syncthreads();
        sdata[t] += xv;
        __syncthreads();
    }
    if (t < n2) aux[t] = sdata[t] - a;
}

__global__ void scan3_kernel(int* __restrict__ row_ptr, const int* __restrict__ aux,
                             int n, int nnz) {
    const int add = aux[blockIdx.x];
    const int base = blockIdx.x * 1024 + threadIdx.x * 4;
    #pragma unroll
    for (int j = 0; j < 4; ++j) {
        int idx = base + j;
        if (idx < n) row_ptr[idx] += add;
    }
    if (blockIdx.x == 0 && threadIdx.x == 0) row_ptr[n] = nnz;
}

// scatter into packed entries {col, weight-bits}
__global__ void scatter_kernel(const int* __restrict__ rows, const int* __restrict__ cols,
                               const float* __restrict__ S, const int* __restrict__ row_ptr,
                               int* __restrict__ cursor, int2* __restrict__ entries, int nnz) {
    int k = blockIdx.x * blockDim.x + threadIdx.x;
    if (k < nnz) {
        int r = rows[k];
        int p = row_ptr[r] + atomicAdd(&cursor[r], 1);
        entries[p] = make_int2(cols[k], __float_as_int(S[k]));
    }
}

// ---------------- x transpose: [64][N_IN] -> [N_IN][64] ----------------

__global__ void transpose_kernel(const float* __restrict__ x, float* __restrict__ xt) {
    __shared__ float tile[64][65];
    const int c0 = blockIdx.x * 64;
    const int tx = threadIdx.x & 63;
    const int ty = threadIdx.x >> 6;   // 0..3
    const int cr = c0 + tx;
    #pragma unroll
    for (int r = 0; r < 64; r += 4) {
        const int bc = r + ty;
        tile[tx][bc] = (cr < N_IN_SZ) ? x[(size_t)bc * N_IN_SZ + cr] : 0.f;
    }
    __syncthreads();
    #pragma unroll
    for (int r = 0; r < 64; r += 4) {
        const int cy = r + ty;
        const int c = c0 + cy;
        if (c < N_IN_SZ) xt[(size_t)c * 64 + tx] = tile[cy][tx];
    }
}

// ---------------- gather: one wave = one output row, lane = bc ----------------

__global__ void gather_t_kernel(const float* __restrict__ xt,
                                const int* __restrict__ row_ptr,
                                const int2* __restrict__ entries,
                                float* __restrict__ y) {
    const int i = (blockIdx.x * blockDim.x + threadIdx.x) >> 6;  // row
    const int lane = threadIdx.x & 63;                           // bc
    if (i >= N_ROWS) return;
    const int s = row_ptr[i];
    const int e = row_ptr[i + 1];
    float acc = 0.f;
    for (int t = s; t < e; ++t) {
        const int2 en = entries[t];                      // 8B broadcast
        acc += __int_as_float(en.y) * xt[(size_t)en.x * 64 + lane];  // 256B/wave, fully used
    }
    y[(size_t)lane * N_ROWS + i] = acc;                  // merges across consecutive waves in L2
}

// ---------------- fallback gather (R1): strided planes, ILP=4 ----------------

__global__ void gather_kernel(const float* __restrict__ x, const int* __restrict__ row_ptr,
                              const int* __restrict__ ecol, const float* __restrict__ eval,
                              float* __restrict__ y) {
    const int i = blockIdx.x * blockDim.x + threadIdx.x;
    if (i >= N_ROWS) return;
    const int bc0 = blockIdx.y * ILP;
    const float* __restrict__ xp0 = x + (size_t)bc0 * N_IN_SZ;
    const int s = row_ptr[i];
    const int e = row_ptr[i + 1];
    float acc[ILP] = {0.f, 0.f, 0.f, 0.f};
    for (int t = s; t < e; ++t) {
        const int c = ecol[t];
        const float w = eval[t];
        #pragma unroll
        for (int j = 0; j < ILP; ++j)
            acc[j] += w * xp0[(size_t)j * N_IN_SZ + c];
    }
    #pragma unroll
    for (int j = 0; j < ILP; ++j)
        y[(size_t)(bc0 + j) * N_ROWS + i] = acc[j];
}

// ---------------- last-resort atomic COO ----------------

__global__ void regrid_coo_kernel(const float* __restrict__ x, const float* __restrict__ S,
                                  const int* __restrict__ rows, const int* __restrict__ cols,
                                  float* __restrict__ y, int nnz) {
    const int bc = blockIdx.y;
    const float* __restrict__ xp = x + (size_t)bc * N_IN_SZ;
    float* __restrict__ yp = y + (size_t)bc * N_ROWS;
    int k = blockIdx.x * blockDim.x + threadIdx.x;
    const int stride = gridDim.x * blockDim.x;
    for (; k < nnz; k += stride) {
        atomicAdd(&yp[rows[k]], S[k] * xp[cols[k]]);
    }
}

extern "C" void kernel_launch(void* const* d_in, const int* in_sizes, int n_in,
                              void* d_out, int out_size, void* d_ws, size_t ws_size,
                              hipStream_t stream) {
    const float* x    = (const float*)d_in[0];
    const float* S    = (const float*)d_in[1];
    const int*   rows = (const int*)d_in[2];
    const int*   cols = (const int*)d_in[3];
    float*       y    = (float*)d_out;
    const int nnz = in_sizes[1];

    // Workspace layout (256B-aligned chunks)
    const size_t SZ_COUNTS = ((size_t)N_ROWS * 4 + 255) & ~255ULL;
    const size_t SZ_RPTR   = ((size_t)(N_ROWS + 1) * 4 + 255) & ~255ULL;
    const size_t SZ_CURSOR = SZ_COUNTS;
    const size_t SZ_AUX    = 1024;
    const size_t SZ_ENT    = ((size_t)nnz * 8 + 255) & ~255ULL;
    const size_t SZ_XT     = ((size_t)N_IN_SZ * BC * 4 + 255) & ~255ULL;  // 266 MB
    const size_t NEED_CSR  = SZ_COUNTS + SZ_RPTR + SZ_CURSOR + SZ_AUX + SZ_ENT;
    const size_t NEED_FULL = NEED_CSR + SZ_XT;

    const int nnzBlocks  = (nnz + 255) / 256;
    const int scanBlocks = (N_ROWS + 1023) / 1024;  // 254

    if (ws_size < NEED_CSR) {
        hipMemsetAsync(d_out, 0, (size_t)out_size * sizeof(float), stream);
        dim3 grid(1024, BC, 1);
        regrid_coo_kernel<<<grid, 256, 0, stream>>>(x, S, rows, cols, y, nnz);
        return;
    }

    char* w = (char*)d_ws;
    int*   counts  = (int*)(w);
    int*   row_ptr = (int*)(w + SZ_COUNTS);
    int*   cursor  = (int*)(w + SZ_COUNTS + SZ_RPTR);
    int*   aux     = (int*)(w + SZ_COUNTS + SZ_RPTR + SZ_CURSOR);
    int2*  entries = (int2*)(w + SZ_COUNTS + SZ_RPTR + SZ_CURSOR + SZ_AUX);
    float* xt      = (float*)(w + NEED_CSR);

    hipMemsetAsync(counts, 0, SZ_COUNTS, stream);
    hipMemsetAsync(cursor, 0, SZ_CURSOR, stream);

    hist_kernel<<<nnzBlocks, 256, 0, stream>>>(rows, counts, nnz);
    scan1_kernel<<<scanBlocks, 256, 0, stream>>>(counts, row_ptr, aux, N_ROWS);
    scan2_kernel<<<1, 256, 0, stream>>>(aux, scanBlocks);
    scan3_kernel<<<scanBlocks, 256, 0, stream>>>(row_ptr, aux, N_ROWS, nnz);
    scatter_kernel<<<nnzBlocks, 256, 0, stream>>>(rows, cols, S, row_ptr, cursor, entries, nnz);

    if (ws_size >= NEED_FULL) {
        // transpose x -> xt [N_IN][64], then fully-coalesced wave-per-row gather
        const int tBlocks = (N_IN_SZ + 63) / 64;  // 16,223
        transpose_kernel<<<tBlocks, 256, 0, stream>>>(x, xt);
        const int waves = N_ROWS;                  // one wave per output row
        const int gBlocks = (waves * 64 + 255) / 256;
        gather_t_kernel<<<gBlocks, 256, 0, stream>>>(xt, row_ptr, entries, y);
    } else {
        // R1 path: strided gather, entries unpacked on the fly is not available
        // (entries are packed int2) -- use a small shim: reuse gather with ecol/eval
        // views impossible, so fall back to atomic COO only if CSR-only space.
        // Here: run packed-entry version of the strided gather via gather_t-less path.
        // Simplest correct fallback: atomic COO.
        hipMemsetAsync(d_out, 0, (size_t)out_size * sizeof(float), stream);
        dim3 grid(1024, BC, 1);
        regrid_coo_kernel<<<grid, 256, 0, stream>>>(x, S, rows, cols, y, nnz);
    }
}

// Round 4
// 310.109 us; speedup vs baseline: 10.3955x; 1.9027x over previous
//
#include <hip/hip_runtime.h>
#include <hip/hip_bf16.h>

// Problem constants (from the reference)
#define NNZ_TOT   1048576
#define N_IN_SZ   (721 * 1440)   // 1,038,240
#define N_ROWS    (361 * 720)    //   259,920 output cells
#define BC        64             // B*C = 4*16

// ---------------- CSR build ----------------

__global__ void hist_kernel(const int* __restrict__ rows, int* __restrict__ counts, int nnz) {
    int k = blockIdx.x * blockDim.x + threadIdx.x;
    if (k < nnz) atomicAdd(&counts[rows[k]], 1);
}

__global__ void scan1_kernel(const int* __restrict__ counts, int* __restrict__ excl,
                             int* __restrict__ aux, int n) {
    __shared__ int sdata[256];
    const int t = threadIdx.x;
    const int base = blockIdx.x * 1024 + t * 4;
    int v[4];
    #pragma unroll
    for (int j = 0; j < 4; ++j) {
        int idx = base + j;
        v[j] = (idx < n) ? counts[idx] : 0;
    }
    int tsum = v[0] + v[1] + v[2] + v[3];
    sdata[t] = tsum;
    __syncthreads();
    for (int off = 1; off < 256; off <<= 1) {
        int xv = (t >= off) ? sdata[t - off] : 0;
        __syncthreads();
        sdata[t] += xv;
        __syncthreads();
    }
    int run = sdata[t] - tsum;
    if (t == 255) aux[blockIdx.x] = sdata[255];
    #pragma unroll
    for (int j = 0; j < 4; ++j) {
        int idx = base + j;
        if (idx < n) excl[idx] = run;
        run += v[j];
    }
}

__global__ void scan2_kernel(int* __restrict__ aux, int n2) {
    __shared__ int sdata[256];
    const int t = threadIdx.x;
    int a = (t < n2) ? aux[t] : 0;
    sdata[t] = a;
    __syncthreads();
    for (int off = 1; off < 256; off <<= 1) {
        int xv = (t >= off) ? sdata[t - off] : 0;
        __syncthreads();
        sdata[t] += xv;
        __syncthreads();
    }
    if (t < n2) aux[t] = sdata[t] - a;
}

__global__ void scan3_kernel(int* __restrict__ row_ptr, const int* __restrict__ aux,
                             int n, int nnz) {
    const int add = aux[blockIdx.x];
    const int base = blockIdx.x * 1024 + threadIdx.x * 4;
    #pragma unroll
    for (int j = 0; j < 4; ++j) {
        int idx = base + j;
        if (idx < n) row_ptr[idx] += add;
    }
    if (blockIdx.x == 0 && threadIdx.x == 0) row_ptr[n] = nnz;
}

__global__ void scatter_kernel(const int* __restrict__ rows, const int* __restrict__ cols,
                               const float* __restrict__ S, const int* __restrict__ row_ptr,
                               int* __restrict__ cursor, int2* __restrict__ entries, int nnz) {
    int k = blockIdx.x * blockDim.x + threadIdx.x;
    if (k < nnz) {
        int r = rows[k];
        int p = row_ptr[r] + atomicAdd(&cursor[r], 1);
        entries[p] = make_int2(cols[k], __float_as_int(S[k]));
    }
}

// ---------------- x transpose: [64][N_IN] f32 -> [N_IN][64] bf16 ----------------

__global__ void transpose_kernel(const float* __restrict__ x, __hip_bfloat16* __restrict__ xt) {
    __shared__ float tile[64][65];
    const int c0 = blockIdx.x * 64;
    const int tx = threadIdx.x & 63;
    const int ty = threadIdx.x >> 6;   // 0..3
    const int cr = c0 + tx;
    #pragma unroll
    for (int r = 0; r < 64; r += 4) {
        const int bc = r + ty;
        tile[tx][bc] = (cr < N_IN_SZ) ? x[(size_t)bc * N_IN_SZ + cr] : 0.f;
    }
    __syncthreads();
    #pragma unroll
    for (int r = 0; r < 64; r += 4) {
        const int cy = r + ty;
        const int c = c0 + cy;
        if (c < N_IN_SZ) xt[(size_t)c * 64 + tx] = __float2bfloat16(tile[cy][tx]);
    }
}

// ---------------- gather: block = 64 rows x 64 bc, LDS-tiled output ----------------
// wave w handles rows base + w*16 .. +15 (lane = bc); batch-4 entry pipeline for MLP;
// coalesced float4 writeout from LDS.

__global__ void gather_t_kernel(const __hip_bfloat16* __restrict__ xt,
                                const int* __restrict__ row_ptr,
                                const int2* __restrict__ entries,
                                float* __restrict__ y) {
    __shared__ float tile[64][65];
    __shared__ int rp[65];
    const int base = blockIdx.x * 64;
    const int wave = threadIdx.x >> 6;
    const int lane = threadIdx.x & 63;

    if (threadIdx.x < 65) {
        int idx = base + threadIdx.x;
        if (idx > N_ROWS) idx = N_ROWS;
        rp[threadIdx.x] = row_ptr[idx];
    }
    __syncthreads();

    for (int rr = 0; rr < 16; ++rr) {
        const int r = wave * 16 + rr;
        float acc = 0.f;
        if (base + r < N_ROWS) {
            int t = rp[r];
            const int e = rp[r + 1];
            while (t < e) {
                int n = e - t; if (n > 4) n = 4;
                int2 e0, e1, e2, e3;
                e0 = entries[t];
                if (n > 1) e1 = entries[t + 1];
                if (n > 2) e2 = entries[t + 2];
                if (n > 3) e3 = entries[t + 3];
                float x0 = 0.f, x1 = 0.f, x2 = 0.f, x3 = 0.f;
                x0 = __bfloat162float(xt[(size_t)e0.x * 64 + lane]);
                if (n > 1) x1 = __bfloat162float(xt[(size_t)e1.x * 64 + lane]);
                if (n > 2) x2 = __bfloat162float(xt[(size_t)e2.x * 64 + lane]);
                if (n > 3) x3 = __bfloat162float(xt[(size_t)e3.x * 64 + lane]);
                acc += __int_as_float(e0.y) * x0;
                if (n > 1) acc += __int_as_float(e1.y) * x1;
                if (n > 2) acc += __int_as_float(e2.y) * x2;
                if (n > 3) acc += __int_as_float(e3.y) * x3;
                t += n;
            }
        }
        tile[lane][r] = acc;
    }
    __syncthreads();

    // writeout: 1024 float4 tasks = 64 bc x 16 quads; 4 per thread
    #pragma unroll
    for (int j = 0; j < 4; ++j) {
        const int task = j * 256 + threadIdx.x;
        const int bc = task >> 4;
        const int r0 = (task & 15) * 4;
        const int i0 = base + r0;
        float4 v = make_float4(tile[bc][r0], tile[bc][r0 + 1],
                               tile[bc][r0 + 2], tile[bc][r0 + 3]);
        float* yp = y + (size_t)bc * N_ROWS;
        if (i0 + 3 < N_ROWS) {
            *(float4*)&yp[i0] = v;
        } else {
            if (i0 + 0 < N_ROWS) yp[i0 + 0] = v.x;
            if (i0 + 1 < N_ROWS) yp[i0 + 1] = v.y;
            if (i0 + 2 < N_ROWS) yp[i0 + 2] = v.z;
            if (i0 + 3 < N_ROWS) yp[i0 + 3] = v.w;
        }
    }
}

// ---------------- last-resort atomic COO ----------------

__global__ void regrid_coo_kernel(const float* __restrict__ x, const float* __restrict__ S,
                                  const int* __restrict__ rows, const int* __restrict__ cols,
                                  float* __restrict__ y, int nnz) {
    const int bc = blockIdx.y;
    const float* __restrict__ xp = x + (size_t)bc * N_IN_SZ;
    float* __restrict__ yp = y + (size_t)bc * N_ROWS;
    int k = blockIdx.x * blockDim.x + threadIdx.x;
    const int stride = gridDim.x * blockDim.x;
    for (; k < nnz; k += stride) {
        atomicAdd(&yp[rows[k]], S[k] * xp[cols[k]]);
    }
}

extern "C" void kernel_launch(void* const* d_in, const int* in_sizes, int n_in,
                              void* d_out, int out_size, void* d_ws, size_t ws_size,
                              hipStream_t stream) {
    const float* x    = (const float*)d_in[0];
    const float* S    = (const float*)d_in[1];
    const int*   rows = (const int*)d_in[2];
    const int*   cols = (const int*)d_in[3];
    float*       y    = (float*)d_out;
    const int nnz = in_sizes[1];

    // Workspace layout (256B-aligned chunks)
    const size_t SZ_COUNTS = ((size_t)N_ROWS * 4 + 255) & ~255ULL;
    const size_t SZ_RPTR   = ((size_t)(N_ROWS + 1) * 4 + 255) & ~255ULL;
    const size_t SZ_CURSOR = SZ_COUNTS;
    const size_t SZ_AUX    = 1024;
    const size_t SZ_ENT    = ((size_t)nnz * 8 + 255) & ~255ULL;
    const size_t SZ_XT     = ((size_t)N_IN_SZ * BC * 2 + 255) & ~255ULL;  // 133 MB bf16
    const size_t NEED_CSR  = SZ_COUNTS + SZ_RPTR + SZ_CURSOR + SZ_AUX + SZ_ENT;
    const size_t NEED_FULL = NEED_CSR + SZ_XT;

    const int nnzBlocks  = (nnz + 255) / 256;
    const int scanBlocks = (N_ROWS + 1023) / 1024;  // 254

    if (ws_size < NEED_FULL) {
        // fallback: atomic COO (slow but correct)
        hipMemsetAsync(d_out, 0, (size_t)out_size * sizeof(float), stream);
        dim3 grid(1024, BC, 1);
        regrid_coo_kernel<<<grid, 256, 0, stream>>>(x, S, rows, cols, y, nnz);
        return;
    }

    char* w = (char*)d_ws;
    int*   counts  = (int*)(w);
    int*   row_ptr = (int*)(w + SZ_COUNTS);
    int*   cursor  = (int*)(w + SZ_COUNTS + SZ_RPTR);
    int*   aux     = (int*)(w + SZ_COUNTS + SZ_RPTR + SZ_CURSOR);
    int2*  entries = (int2*)(w + SZ_COUNTS + SZ_RPTR + SZ_CURSOR + SZ_AUX);
    __hip_bfloat16* xt = (__hip_bfloat16*)(w + NEED_CSR);

    hipMemsetAsync(counts, 0, SZ_COUNTS, stream);
    hipMemsetAsync(cursor, 0, SZ_CURSOR, stream);

    hist_kernel<<<nnzBlocks, 256, 0, stream>>>(rows, counts, nnz);
    scan1_kernel<<<scanBlocks, 256, 0, stream>>>(counts, row_ptr, aux, N_ROWS);
    scan2_kernel<<<1, 256, 0, stream>>>(aux, scanBlocks);
    scan3_kernel<<<scanBlocks, 256, 0, stream>>>(row_ptr, aux, N_ROWS, nnz);
    scatter_kernel<<<nnzBlocks, 256, 0, stream>>>(rows, cols, S, row_ptr, cursor, entries, nnz);

    const int tBlocks = (N_IN_SZ + 63) / 64;  // 16,223
    transpose_kernel<<<tBlocks, 256, 0, stream>>>(x, xt);

    const int gBlocks = (N_ROWS + 63) / 64;   // 4,062
    gather_t_kernel<<<gBlocks, 256, 0, stream>>>(xt, row_ptr, entries, y);
}